// Round 17
// baseline (780.776 us; speedup 1.0000x reference)
//
#include <hip/hip_runtime.h>
#include <hip/hip_bf16.h>
#include <math.h>

typedef short s16x8 __attribute__((ext_vector_type(8)));
typedef float f32x4 __attribute__((ext_vector_type(4)));
typedef __hip_bfloat16 bf16;

#define NTOK 4096
#define S_LEN 2048
#define HID_C 1024
#define E_C 8
#define INTER_C 2816
#define WIN_C 64
#define CAP 4096
#define NQKV 1536
#define K2C 2048
#define ATILE 16
#define KR 80
#define OUT0_N ((size_t)NTOK*HID_C)

#define AS1 __attribute__((address_space(1)))
#define AS3 __attribute__((address_space(3)))

static __device__ __forceinline__ void gload16(const void* g, void* l){
    __builtin_amdgcn_global_load_lds((AS1 void*)(g), (AS3 void*)(l), 16, 0, 0);
}

static __device__ __forceinline__ float b2f(bf16 v){ return __bfloat162float(v); }
static __device__ __forceinline__ bf16  f2b(float v){ return __float2bfloat16(v); }
static __device__ __forceinline__ short f2bs(float v){ bf16 h = __float2bfloat16(v); return *reinterpret_cast<short*>(&h); }
struct SplitBF { short hi; short lo; };
static __device__ __forceinline__ SplitBF splitf(float x){
    SplitBF r;
    bf16 bh = __float2bfloat16(x);
    r.hi = *reinterpret_cast<short*>(&bh);
    float rem = x - __bfloat162float(bh);
    bf16 bl = __float2bfloat16(rem);
    r.lo = *reinterpret_cast<short*>(&bl);
    return r;
}

// Swizzle convention: within each 64-short (128B) group of a row, logical
// 8-short chunk c is stored at physical chunk c ^ (row & 7).

// ---------------- device bodies ----------------

static __device__ __forceinline__ void tsplit_body(char* smem, const float* __restrict__ src,
                                                   short* __restrict__ dst, int N, int row_off,
                                                   int bx, int by){
    float (*tile)[33] = (float(*)[33])smem;
    const int n0 = bx*32, k0 = by*32;
    const int tx = threadIdx.x & 31, ty = threadIdx.x >> 5;
    #pragma unroll
    for (int i = 0; i < 4; ++i)
        tile[ty + i*8][tx] = src[(size_t)(k0 + ty + i*8)*N + n0 + tx];
    __syncthreads();
    const int g = k0 >> 5;
    const int chH = tx >> 3, chL = 4 | (tx >> 3), off = tx & 7;
    #pragma unroll
    for (int i = 0; i < 4; ++i){
        int nn = ty + i*8;
        SplitBF s = splitf(tile[tx][nn]);
        size_t rowb = (size_t)(row_off + n0 + nn)*K2C + g*64;
        dst[rowb + ((chH ^ ty)<<3) + off] = s.hi;
        dst[rowb + ((chL ^ ty)<<3) + off] = s.lo;
    }
}

static __device__ __forceinline__ void rmsn1_body(char* smem, const float* __restrict__ xin,
                                                  const float* __restrict__ w,
                                                  short* __restrict__ oc, int t){
    float* red = (float*)smem;
    const int tid = threadIdx.x;
    float4 v = *(const float4*)(xin + (size_t)t*HID_C + tid*4);
    float x[4] = {v.x, v.y, v.z, v.w};
    float s = x[0]*x[0]+x[1]*x[1]+x[2]*x[2]+x[3]*x[3];
    #pragma unroll
    for (int off=32; off; off>>=1) s += __shfl_xor(s, off);
    if ((tid&63)==0) red[tid>>6] = s;
    __syncthreads();
    float tot = red[0]+red[1]+red[2]+red[3];
    float sc = rsqrtf(tot*(1.0f/HID_C) + 1e-8f);
    float4 wv = *(const float4*)(w + tid*4);
    float o[4] = { x[0]*sc*wv.x, x[1]*sc*wv.y, x[2]*sc*wv.z, x[3]*sc*wv.w };
    __align__(8) short th[4], tl[4];
    #pragma unroll
    for (int i=0;i<4;++i){ SplitBF sp = splitf(o[i]); th[i]=sp.hi; tl[i]=sp.lo; }
    const int g = tid>>3, q = tid&7;
    const int ch = q>>1, sub = (q&1)*4, key = t&7;
    short* rowp = oc + (size_t)t*K2C + g*64;
    *(uint2*)(rowp + ((ch ^ key)<<3) + sub)      = *(uint2*)th;
    *(uint2*)(rowp + (((4|ch) ^ key)<<3) + sub)  = *(uint2*)tl;
}

static __device__ __forceinline__ void tbf16_body(char* smem, const float* __restrict__ src0,
                                                  short* __restrict__ dst0, int K, int N,
                                                  int bx, int by, int e){
    const float* src = src0 + (size_t)e*K*N;
    short* dst = dst0 + (size_t)e*N*K;
    float (*tile)[65] = (float(*)[65])smem;
    const int n0 = bx*64, k0 = by*64;
    const int tid = threadIdx.x;
    #pragma unroll
    for (int i = 0; i < 16; ++i){
        int idx = tid + i*256;
        int k = idx >> 6, n = idx & 63;
        tile[k][n] = src[(size_t)(k0 + k)*N + n0 + n];
    }
    __syncthreads();
    const int grp = k0 >> 6;
    const int ch  = tid & 7;
    #pragma unroll
    for (int i = 0; i < 2; ++i){
        int nn = (tid >> 3) + i*32;
        int key = nn & 7;
        __align__(16) short vals[8];
        #pragma unroll
        for (int c = 0; c < 8; ++c) vals[c] = f2bs(tile[ch*8 + c][nn]);
        *(uint4*)(dst + (size_t)(n0 + nn)*K + grp*64 + ((ch ^ key)<<3)) = *(uint4*)vals;
    }
}

template<bool RESID>
static __device__ __forceinline__ void sgemm_body(char* smem, int bmi, int bni,
                                                  const short* __restrict__ A2,
                                                  const short* __restrict__ B2,
                                                  float* __restrict__ C,
                                                  const float* __restrict__ resid, int N){
    short* lA0 = (short*)smem;
    short* lB0 = (short*)(smem + 32768);
    const int tid = threadIdx.x;
    const int bm0 = bmi*128, bn0 = bni*128;
    const int l = tid & 63, w = tid >> 6, wr = w >> 1, wc = w & 1;
    const int lr = l >> 3, lc8 = (l & 7)*8;
    f32x4 acc[4][4] = {};
    auto STAGE = [&](int buf, int kt){
        #pragma unroll
        for (int j = 0; j < 4; ++j){
            int row = w*32 + j*8 + lr;
            gload16(A2 + (size_t)(bm0 + row)*K2C + kt*64 + lc8, lA0 + buf*8192 + (w*32 + j*8)*64);
            gload16(B2 + (size_t)(bn0 + row)*K2C + kt*64 + lc8, lB0 + buf*8192 + (w*32 + j*8)*64);
        }
    };
    STAGE(0, 0);
    for (int kt = 0; kt < 32; ++kt){
        const int cur = kt & 1;
        if (kt + 1 < 32){
            STAGE(cur ^ 1, kt + 1);
            asm volatile("s_waitcnt vmcnt(8)" ::: "memory");
        } else {
            asm volatile("s_waitcnt vmcnt(0)" ::: "memory");
        }
        __builtin_amdgcn_s_barrier();
        __builtin_amdgcn_sched_barrier(0);
        s16x8 ah[4], al[4], bh[4], bl[4];
        #pragma unroll
        for (int mi = 0; mi < 4; ++mi){
            int r = wr*64 + mi*16 + (l&15);
            int key = r & 7;
            ah[mi] = *(const s16x8*)(lA0 + cur*8192 + r*64 + (((l>>4) ^ key)<<3));
            al[mi] = *(const s16x8*)(lA0 + cur*8192 + r*64 + (((4|(l>>4)) ^ key)<<3));
        }
        #pragma unroll
        for (int ni = 0; ni < 4; ++ni){
            int n = wc*64 + ni*16 + (l&15);
            int key = n & 7;
            bh[ni] = *(const s16x8*)(lB0 + cur*8192 + n*64 + (((l>>4) ^ key)<<3));
            bl[ni] = *(const s16x8*)(lB0 + cur*8192 + n*64 + (((4|(l>>4)) ^ key)<<3));
        }
        #pragma unroll
        for (int mi = 0; mi < 4; ++mi)
            #pragma unroll
            for (int ni = 0; ni < 4; ++ni){
                acc[mi][ni] = __builtin_amdgcn_mfma_f32_16x16x32_bf16(ah[mi], bh[ni], acc[mi][ni], 0,0,0);
                acc[mi][ni] = __builtin_amdgcn_mfma_f32_16x16x32_bf16(ah[mi], bl[ni], acc[mi][ni], 0,0,0);
                acc[mi][ni] = __builtin_amdgcn_mfma_f32_16x16x32_bf16(al[mi], bh[ni], acc[mi][ni], 0,0,0);
            }
        __builtin_amdgcn_s_barrier();
    }
    #pragma unroll
    for (int mi = 0; mi < 4; ++mi)
        #pragma unroll
        for (int ni = 0; ni < 4; ++ni)
            #pragma unroll
            for (int rr = 0; rr < 4; ++rr){
                int row = bm0 + wr*64 + mi*16 + (l>>4)*4 + rr;
                int col = bn0 + wc*64 + ni*16 + (l&15);
                float vv = acc[mi][ni][rr];
                if (RESID) vv += resid[(size_t)row*N + col];
                C[(size_t)row*N + col] = vv;
            }
}

// ---------------- fused prepass 1 ----------------
__global__ __launch_bounds__(256) void prep1_k(const float* __restrict__ hidden,
                                               const float* __restrict__ n1w,
                                               short* __restrict__ h1c,
                                               const float* __restrict__ wq,
                                               const float* __restrict__ wk,
                                               const float* __restrict__ wv,
                                               const float* __restrict__ wo,
                                               short* __restrict__ wqkv2,
                                               short* __restrict__ wo2){
    __shared__ __align__(16) char smem[4352];
    const int b = blockIdx.x;
    if (b < 4096){
        rmsn1_body(smem, hidden, n1w, h1c, b);
    } else if (b < 5120){
        int r = b - 4096;
        tsplit_body(smem, wq, wqkv2, 1024, 0, r & 31, r >> 5);
    } else if (b < 5376){
        int r = b - 5120;
        tsplit_body(smem, wk, wqkv2, 256, 1024, r & 7, r >> 3);
    } else if (b < 5632){
        int r = b - 5376;
        tsplit_body(smem, wv, wqkv2, 256, 1280, r & 7, r >> 3);
    } else {
        int r = b - 5632;
        tsplit_body(smem, wo, wo2, 1024, 0, r & 31, r >> 5);
    }
}

// ---------------- fused prepass 2 ----------------
__global__ __launch_bounds__(256) void prep2_k(const short* __restrict__ h1c,
                                               const short* __restrict__ wqkv2,
                                               float* __restrict__ qkvf,
                                               const float* __restrict__ gatew,
                                               const float* __restrict__ upw,
                                               const float* __restrict__ downw,
                                               short* __restrict__ gate_t,
                                               short* __restrict__ up_t,
                                               short* __restrict__ down_t){
    __shared__ __align__(16) char smem[65536];
    const int b = blockIdx.x;
    if (b < 384){
        sgemm_body<false>(smem, b & 31, b >> 5, h1c, wqkv2, qkvf, nullptr, NQKV);
        return;
    }
    int r = b - 384;
    int wsel = r / 5632;
    int r2 = r % 5632;
    if (wsel == 0)      tbf16_body(smem, gatew, gate_t, 1024, 2816, r2 % 44, (r2/44) % 16, r2/704);
    else if (wsel == 1) tbf16_body(smem, upw,   up_t,   1024, 2816, r2 % 44, (r2/44) % 16, r2/704);
    else                tbf16_body(smem, downw, down_t, 2816, 1024, r2 % 16, (r2/16) % 44, r2/704);
}

template<bool RESID>
__global__ __launch_bounds__(256) void sgemm4_k(const short* __restrict__ A2,
                                                const short* __restrict__ B2,
                                                float* __restrict__ C, const float* __restrict__ resid,
                                                int N){
    __shared__ __align__(16) char smem[65536];
    sgemm_body<RESID>(smem, blockIdx.x, blockIdx.y, A2, B2, C, resid, N);
}

__global__ __launch_bounds__(256) void rmsn2_k(const float* __restrict__ xin,
                                               const float* __restrict__ w,
                                               float* __restrict__ outf, bf16* __restrict__ outb,
                                               float* __restrict__ outc){
    const int t = blockIdx.x, tid = threadIdx.x;
    float4 v = *(const float4*)(xin + (size_t)t*HID_C + tid*4);
    float x[4] = {v.x, v.y, v.z, v.w};
    float s = x[0]*x[0]+x[1]*x[1]+x[2]*x[2]+x[3]*x[3];
    #pragma unroll
    for (int off=32; off; off>>=1) s += __shfl_xor(s, off);
    __shared__ float red[4];
    if ((tid&63)==0) red[tid>>6] = s;
    __syncthreads();
    float tot = red[0]+red[1]+red[2]+red[3];
    float sc = rsqrtf(tot*(1.0f/HID_C) + 1e-8f);
    float4 wv = *(const float4*)(w + tid*4);
    float o[4] = { x[0]*sc*wv.x, x[1]*sc*wv.y, x[2]*sc*wv.z, x[3]*sc*wv.w };
    *(float4*)(outf + (size_t)t*HID_C + tid*4) = make_float4(o[0],o[1],o[2],o[3]);
    __align__(8) bf16 tmp[4] = { f2b(o[0]), f2b(o[1]), f2b(o[2]), f2b(o[3]) };
    *(uint2*)(outb + (size_t)t*HID_C + tid*4) = *(uint2*)tmp;
    *(float4*)(outc + (size_t)t*HID_C + tid*4) = v;
}

__global__ __launch_bounds__(256) void rope2_k(float* __restrict__ qkv,
                                               const float* __restrict__ cosb, const float* __restrict__ sinb){
    int idx = blockIdx.x*256 + threadIdx.x;
    int t = idx / 640;
    int r = idx - t*640;
    int hs = r >> 5, tp = r & 31;
    int s = t & (S_LEN-1);
    float c  = cosb[s*32+tp];
    float sn = sinb[s*32+tp];
    float* base;
    if (hs < 16) base = qkv + (size_t)t*NQKV + hs*64 + 2*tp;
    else         base = qkv + (size_t)t*NQKV + 1024 + (hs-16)*64 + 2*tp;
    float2 v = *(float2*)base;
    *(float2*)base = make_float2(v.x*c - v.y*sn, v.x*sn + v.y*c);
}

__global__ __launch_bounds__(256) void attn3_k(const float* __restrict__ qkv,
                                               short* __restrict__ oc){
    const int t0 = blockIdx.x * ATILE;
    const int hk = blockIdx.y;
    const int sq0 = t0 & (S_LEN-1);
    const int tokbase = t0 - sq0;
    const int tid = threadIdx.x, l = tid & 63, w = tid >> 6;
    __shared__ float Kl[KR*65];
    __shared__ float Vl[KR*65];
    __shared__ float qsh[4][64];
    __shared__ float ps[4][64];
    for (int rr = tid >> 4; rr < KR; rr += 16){
        int c4 = (tid & 15)*4;
        int kp = sq0 - 64 + rr;
        float4 kv = make_float4(0,0,0,0), vv = kv;
        if (kp >= 0){
            const float* base = qkv + (size_t)(tokbase + kp)*NQKV + 1024 + hk*64 + c4;
            kv = *(const float4*)base;
            vv = *(const float4*)(base + 256);
        }
        Kl[rr*65 + c4+0]=kv.x; Kl[rr*65 + c4+1]=kv.y; Kl[rr*65 + c4+2]=kv.z; Kl[rr*65 + c4+3]=kv.w;
        Vl[rr*65 + c4+0]=vv.x; Vl[rr*65 + c4+1]=vv.y; Vl[rr*65 + c4+2]=vv.z; Vl[rr*65 + c4+3]=vv.w;
    }
    __syncthreads();
    const int h = hk*4 + w;
    for (int i = 0; i < ATILE; ++i){
        const int t = t0 + i, sq = sq0 + i;
        qsh[w][l] = qkv[(size_t)t*NQKV + h*64 + l];
        float d = 0.f;
        const float* krow = &Kl[(i + l)*65];
        #pragma unroll
        for (int c = 0; c < 64; ++c) d += qsh[w][c] * krow[c];
        const bool valid = (sq - 64 + l) >= 0;
        float sc = valid ? d*0.125f : -1e30f;
        float part = qsh[w][l] * Kl[(i + 64)*65 + l];
        #pragma unroll
        for (int off = 32; off; off >>= 1) part += __shfl_xor(part, off);
        float dg = part*0.125f;
        float m = sc;
        #pragma unroll
        for (int off = 32; off; off >>= 1) m = fmaxf(m, __shfl_xor(m, off));
        m = fmaxf(m, dg);
        float e = __expf(sc - m);
        float ssum = e;
        #pragma unroll
        for (int off = 32; off; off >>= 1) ssum += __shfl_xor(ssum, off);
        float edg = __expf(dg - m);
        ssum += edg;
        float inv = 1.f / ssum;
        ps[w][l] = e * inv;
        float pdg = edg * inv;
        float acc = 0.f;
        #pragma unroll 8
        for (int jj = 0; jj < 64; ++jj) acc += ps[w][jj] * Vl[(i + jj)*65 + l];
        acc += pdg * Vl[(i + 64)*65 + l];
        SplitBF sp = splitf(acc);
        const int k = h*64 + l;
        const int g = k>>5, ch = (k&31)>>3, off2 = k&7, key = t&7;
        short* rowp = oc + (size_t)t*K2C + g*64;
        rowp[((ch ^ key)<<3) + off2]     = sp.hi;
        rowp[(((4|ch) ^ key)<<3) + off2] = sp.lo;
    }
}

__global__ __launch_bounds__(256) void router2_k(const float* __restrict__ h2f, const float* __restrict__ rw,
                                                 int* __restrict__ lists, float* __restrict__ wl,
                                                 int* __restrict__ cnt, float* __restrict__ psum){
    const int tid = threadIdx.x, l = tid & 63, w = tid >> 6;
    __shared__ int   sE0[16], sE1[16], sSlot0[16], sSlot1[16];
    __shared__ float sW0[16], sW1[16];
    __shared__ float sPsum[8];
    __shared__ int   sCnt[8], sBase[8];
    if (tid < 8){ sPsum[tid] = 0.f; sCnt[tid] = 0; }
    __syncthreads();
    #pragma unroll
    for (int i = 0; i < 4; ++i){
        const int li = w*4 + i;
        const int t = blockIdx.x*16 + li;
        float lg[8] = {0,0,0,0,0,0,0,0};
        for (int c = 0; c < 16; ++c){
            int kidx = l + c*64;
            float x = h2f[(size_t)t*HID_C + kidx];
            float4 w0 = *(const float4*)(rw + (size_t)kidx*8);
            float4 w1 = *(const float4*)(rw + (size_t)kidx*8 + 4);
            lg[0] += x*w0.x; lg[1] += x*w0.y; lg[2] += x*w0.z; lg[3] += x*w0.w;
            lg[4] += x*w1.x; lg[5] += x*w1.y; lg[6] += x*w1.z; lg[7] += x*w1.w;
        }
        #pragma unroll
        for (int e = 0; e < 8; ++e)
            #pragma unroll
            for (int off=32; off; off>>=1) lg[e] += __shfl_xor(lg[e], off);
        if (l == 0){
            float m = lg[0];
            #pragma unroll
            for (int e = 1; e < 8; ++e) m = fmaxf(m, lg[e]);
            float p[8]; float s = 0.f;
            #pragma unroll
            for (int e = 0; e < 8; ++e){ p[e] = __expf(lg[e]-m); s += p[e]; }
            float invs = 1.f/s;
            #pragma unroll
            for (int e = 0; e < 8; ++e){ p[e] *= invs; atomicAdd(&sPsum[e], p[e]); }
            float best = -1e30f, sec = -1e30f; int bi = 0, si = 0;
            #pragma unroll
            for (int e = 0; e < 8; ++e){
                float pv = p[e];
                if (pv > best){ sec = best; si = bi; best = pv; bi = e; }
                else if (pv > sec){ sec = pv; si = e; }
            }
            float wsum = best + sec + 1e-9f;
            sE0[li] = bi; sE1[li] = si;
            sW0[li] = best/wsum; sW1[li] = sec/wsum;
            sSlot0[li] = atomicAdd(&sCnt[bi], 1);
            sSlot1[li] = atomicAdd(&sCnt[si], 1);
        }
    }
    __syncthreads();
    if (tid < 8){
        sBase[tid] = atomicAdd(&cnt[tid], sCnt[tid]);
        atomicAdd(&psum[tid], sPsum[tid]);
    }
    __syncthreads();
    if (tid < 16){
        int t = blockIdx.x*16 + tid;
        int e0 = sE0[tid], e1 = sE1[tid];
        int s0 = sBase[e0] + sSlot0[tid];
        int s1 = sBase[e1] + sSlot1[tid];
        lists[e0*CAP + s0] = t; wl[e0*CAP + s0] = sW0[tid];
        lists[e1*CAP + s1] = t; wl[e1*CAP + s1] = sW1[tid];
    }
}

__global__ void finalize_k(const int* __restrict__ cnt, const float* __restrict__ psum,
                           int* __restrict__ offs, float* __restrict__ out){
    if (threadIdx.x == 0 && blockIdx.x == 0){
        int o = 0; float loss = 0.f;
        for (int e = 0; e < 8; ++e){
            offs[e] = o; o += cnt[e];
            loss += (psum[e]*(1.0f/NTOK)) * ((float)cnt[e]*(1.0f/NTOK));
        }
        offs[8] = o;
        out[OUT0_N] = loss * (float)E_C * 0.01f;
    }
}

// ============ MoE gate/up: BM=128, 128 gate + 128 up cols, waves 2x2, wave tile 64x128-eff ============
__global__ __launch_bounds__(256) void moe1g5_k(const short* __restrict__ h2b,
                                                const short* __restrict__ gate_t,
                                                const short* __restrict__ up_t,
                                                bf16* __restrict__ inter,
                                                const int* __restrict__ lists,
                                                const int* __restrict__ cnt,
                                                const int* __restrict__ offs){
    const int b = blockIdx.x;
    const int r = b & 7, j = b >> 3;
    const int G = r + ((j >> 5) << 3);          // 176 groups: e*22 + bn
    const int e = G / 22, bnG = G % 22;
    const int bm0 = (j & 31) * 128;
    const int ne = cnt[e];
    if (bm0 >= ne) return;
    const int bn0 = bnG * 128;
    __shared__ __align__(16) short lA[2][128*64];
    __shared__ __align__(16) short lG[2][128*64];
    __shared__ __align__(16) short lU[2][128*64];
    const int tid = threadIdx.x;
    const int l = tid & 63, w = tid >> 6, wr = w >> 1, wc = w & 1;
    const int lr = l >> 3, lc8 = (l & 7)*8;
    const int lcs = (((l & 7) ^ lr) << 3);
    const short* Gb = gate_t + (size_t)e*INTER_C*HID_C;
    const short* Ub = up_t   + (size_t)e*INTER_C*HID_C;
    int tokA[4];
    #pragma unroll
    for (int jj = 0; jj < 4; ++jj){
        int slot = bm0 + w*32 + jj*8 + lr;
        if (slot >= ne) slot = ne - 1;
        tokA[jj] = lists[e*CAP + slot];
    }
    auto STAGE = [&](int buf, int kt){
        #pragma unroll
        for (int jj = 0; jj < 4; ++jj){
            int row = w*32 + jj*8 + lr;
            gload16(h2b + (size_t)tokA[jj]*HID_C + kt*64 + lcs, &lA[buf][(w*32 + jj*8)*64]);
            gload16(Gb + (size_t)(bn0 + row)*HID_C + kt*64 + lc8, &lG[buf][(w*32 + jj*8)*64]);
            gload16(Ub + (size_t)(bn0 + row)*HID_C + kt*64 + lc8, &lU[buf][(w*32 + jj*8)*64]);
        }
    };
    f32x4 ag[4][4] = {}; f32x4 au[4][4] = {};
    STAGE(0, 0);
    for (int kt = 0; kt < 16; ++kt){
        const int cur = kt & 1;
        if (kt + 1 < 16){
            STAGE(cur ^ 1, kt + 1);
            asm volatile("s_waitcnt vmcnt(12)" ::: "memory");
        } else {
            asm volatile("s_waitcnt vmcnt(0)" ::: "memory");
        }
        __builtin_amdgcn_s_barrier();
        __builtin_amdgcn_sched_barrier(0);
        __builtin_amdgcn_s_setprio(1);
        #pragma unroll
        for (int kk = 0; kk < 64; kk += 32){
            s16x8 af[4], bg[4], bu[4];
            #pragma unroll
            for (int mi = 0; mi < 4; ++mi){
                int ra = wr*64 + mi*16 + (l&15);
                int chA = (kk>>3) + (l>>4);
                af[mi] = *(const s16x8*)(&lA[cur][ra*64 + ((chA ^ (ra&7))<<3)]);
            }
            #pragma unroll
            for (int ni = 0; ni < 4; ++ni){
                int n = wc*64 + ni*16 + (l&15);
                int ch = (kk>>3) + (l>>4);
                bg[ni] = *(const s16x8*)(&lG[cur][n*64 + ((ch ^ (n&7))<<3)]);
                bu[ni] = *(const s16x8*)(&lU[cur][n*64 + ((ch ^ (n&7))<<3)]);
            }
            #pragma unroll
            for (int mi = 0; mi < 4; ++mi)
                #pragma unroll
                for (int ni = 0; ni < 4; ++ni){
                    ag[mi][ni] = __builtin_amdgcn_mfma_f32_16x16x32_bf16(af[mi], bg[ni], ag[mi][ni], 0,0,0);
                    au[mi][ni] = __builtin_amdgcn_mfma_f32_16x16x32_bf16(af[mi], bu[ni], au[mi][ni], 0,0,0);
                }
        }
        __builtin_amdgcn_s_setprio(0);
        __builtin_amdgcn_s_barrier();
    }
    const int obase = offs[e];
    #pragma unroll
    for (int mi = 0; mi < 4; ++mi)
        #pragma unroll
        for (int ni = 0; ni < 4; ++ni)
            #pragma unroll
            for (int rr = 0; rr < 4; ++rr){
                int slot = bm0 + wr*64 + mi*16 + (l>>4)*4 + rr;
                if (slot < ne){
                    int col = bn0 + wc*64 + ni*16 + (l&15);
                    float g = ag[mi][ni][rr], uu = au[mi][ni][rr];
                    float val = (g/(1.f+__expf(-g)))*uu;
                    inter[(size_t)(obase+slot)*INTER_C + col] = f2b(val);
                }
            }
}

// ============ MoE down: BM=128, BN=256, waves 2x2, wave tile 64x128 ============
__global__ __launch_bounds__(256) void moe2g5_k(const bf16* __restrict__ inter,
                                                const short* __restrict__ down_t,
                                                float* __restrict__ outp,
                                                const float* __restrict__ wl,
                                                const int* __restrict__ lists,
                                                const int* __restrict__ cnt,
                                                const int* __restrict__ offs){
    const int b = blockIdx.x;
    const int r = b & 7, j = b >> 3;
    const int G = r + ((j >> 5) << 3);          // 32 groups: e*4 + bn
    const int e = G >> 2, bnG = G & 3;
    const int bm0 = (j & 31) * 128;
    const int ne = cnt[e];
    if (bm0 >= ne) return;
    const int bn0 = bnG * 256;
    __shared__ __align__(16) short lA[2][128*64];
    __shared__ __align__(16) short lB[2][256*64];
    const int tid = threadIdx.x;
    const int l = tid & 63, w = tid >> 6, wr = w >> 1, wc = w & 1;
    const int lr = l >> 3, lc8 = (l & 7)*8;
    const int lcs = (((l & 7) ^ lr) << 3);
    const int obase = offs[e];
    const short* Db = down_t + (size_t)e*HID_C*INTER_C;
    const short* As = (const short*)inter;
    int rowA[4];
    #pragma unroll
    for (int jj = 0; jj < 4; ++jj){
        int slot = bm0 + w*32 + jj*8 + lr;
        if (slot >= ne) slot = ne - 1;
        rowA[jj] = obase + slot;
    }
    auto STAGE = [&](int buf, int kt){
        #pragma unroll
        for (int jj = 0; jj < 4; ++jj)
            gload16(As + (size_t)rowA[jj]*INTER_C + kt*64 + lcs, &lA[buf][(w*32 + jj*8)*64]);
        #pragma unroll
        for (int jj = 0; jj < 8; ++jj){
            int n = w*64 + jj*8 + lr;
            gload16(Db + (size_t)(bn0 + n)*INTER_C + kt*64 + lc8, &lB[buf][(w*64 + jj*8)*64]);
        }
    };
    f32x4 acc[4][8] = {};
    STAGE(0, 0);
    for (int kt = 0; kt < 44; ++kt){
        const int cur = kt & 1;
        if (kt + 1 < 44){
            STAGE(cur ^ 1, kt + 1);
            asm volatile("s_waitcnt vmcnt(12)" ::: "memory");
        } else {
            asm volatile("s_waitcnt vmcnt(0)" ::: "memory");
        }
        __builtin_amdgcn_s_barrier();
        __builtin_amdgcn_sched_barrier(0);
        __builtin_amdgcn_s_setprio(1);
        #pragma unroll
        for (int kk = 0; kk < 64; kk += 32){
            s16x8 af[4], bfr[8];
            #pragma unroll
            for (int mi = 0; mi < 4; ++mi){
                int ra = wr*64 + mi*16 + (l&15);
                int chA = (kk>>3) + (l>>4);
                af[mi] = *(const s16x8*)(&lA[cur][ra*64 + ((chA ^ (ra&7))<<3)]);
            }
            #pragma unroll
            for (int ni = 0; ni < 8; ++ni){
                int n = wc*128 + ni*16 + (l&15);
                int ch = (kk>>3) + (l>>4);
                bfr[ni] = *(const s16x8*)(&lB[cur][n*64 + ((ch ^ (n&7))<<3)]);
            }
            #pragma unroll
            for (int mi = 0; mi < 4; ++mi)
                #pragma unroll
                for (int ni = 0; ni < 8; ++ni)
                    acc[mi][ni] = __builtin_amdgcn_mfma_f32_16x16x32_bf16(af[mi], bfr[ni], acc[mi][ni], 0,0,0);
        }
        __builtin_amdgcn_s_setprio(0);
        __builtin_amdgcn_s_barrier();
    }
    #pragma unroll
    for (int mi = 0; mi < 4; ++mi)
        #pragma unroll
        for (int ni = 0; ni < 8; ++ni)
            #pragma unroll
            for (int rr = 0; rr < 4; ++rr){
                int slot = bm0 + wr*64 + mi*16 + (l>>4)*4 + rr;
                if (slot < ne){
                    int col = bn0 + wc*128 + ni*16 + (l&15);
                    int tok = lists[e*CAP + slot];
                    float wgt = wl[e*CAP + slot];
                    atomicAdd(&outp[(size_t)tok*HID_C + col], acc[mi][ni][rr]*wgt);
                }
            }
}

// ======================= HOST =======================
extern "C" void kernel_launch(void* const* d_in, const int* in_sizes, int n_in,
                              void* d_out, int out_size, void* d_ws, size_t ws_size,
                              hipStream_t stream){
    const float* hidden  = (const float*)d_in[0];
    const float* fcos    = (const float*)d_in[1];
    const float* fsin    = (const float*)d_in[2];
    const float* wq      = (const float*)d_in[3];
    const float* wk      = (const float*)d_in[4];
    const float* wv      = (const float*)d_in[5];
    const float* wo      = (const float*)d_in[6];
    const float* routerw = (const float*)d_in[7];
    const float* gatew   = (const float*)d_in[8];
    const float* upw     = (const float*)d_in[9];
    const float* downw   = (const float*)d_in[10];
    const float* n1w     = (const float*)d_in[11];
    const float* n2w     = (const float*)d_in[12];

    char* p = (char*)d_ws;
    size_t off = 0;
    auto alloc = [&](size_t b)->void*{ void* r = p + off; off = (off + b + 255) & ~(size_t)255; return r; };

    int*   cnt    = (int*)alloc(64);
    float* psum   = (float*)alloc(64);
    int*   offs   = (int*)alloc(64);
    int*   lists  = (int*)alloc((size_t)E_C*CAP*4);
    float* wl     = (float*)alloc((size_t)E_C*CAP*4);
    short* wqkv2  = (short*)alloc((size_t)NQKV*K2C*2);
    short* wo2    = (short*)alloc((size_t)HID_C*K2C*2);
    short* gate_t = (short*)alloc((size_t)E_C*INTER_C*HID_C*2);
    short* up_t   = (short*)alloc((size_t)E_C*INTER_C*HID_C*2);
    short* down_t = (short*)alloc((size_t)E_C*HID_C*INTER_C*2);
    short* h1c    = (short*)alloc((size_t)NTOK*K2C*2);
    float* qkvf   = (float*)alloc((size_t)NTOK*NQKV*4);
    float* hres   = (float*)alloc((size_t)NTOK*HID_C*4);
    bf16*  inter  = (bf16*)alloc((size_t)2*NTOK*INTER_C*2);

    short* oc  = h1c;
    float* h2f = qkvf;
    bf16*  h2b = (bf16*)(qkvf + (size_t)NTOK*HID_C);
    float* outp = (float*)d_out;

    (void)hipMemsetAsync(cnt, 0, 64, stream);
    (void)hipMemsetAsync(psum, 0, 64, stream);

    prep1_k<<<6656, 256, 0, stream>>>(hidden, n1w, h1c, wq, wk, wv, wo, wqkv2, wo2);
    prep2_k<<<384 + 16896, 256, 0, stream>>>(h1c, wqkv2, qkvf, gatew, upw, downw, gate_t, up_t, down_t);
    rope2_k<<<10240, 256, 0, stream>>>(qkvf, fcos, fsin);
    attn3_k<<<dim3(NTOK/ATILE, 4), 256, 0, stream>>>(qkvf, oc);
    sgemm4_k<true><<<dim3(32,8), 256, 0, stream>>>(oc, wo2, hres, hidden, 1024);
    rmsn2_k<<<NTOK, 256, 0, stream>>>(hres, n2w, h2f, h2b, outp);
    router2_k<<<256, 256, 0, stream>>>(h2f, routerw, lists, wl, cnt, psum);
    finalize_k<<<1, 64, 0, stream>>>(cnt, psum, offs, outp);
    moe1g5_k<<<5632, 256, 0, stream>>>((const short*)h2b, gate_t, up_t, inter, lists, cnt, offs);
    moe2g5_k<<<1024, 256, 0, stream>>>(inter, down_t, outp, wl, lists, cnt, offs);
}

// Round 18
// 618.800 us; speedup vs baseline: 1.2618x; 1.2618x over previous
//
#include <hip/hip_runtime.h>
#include <hip/hip_bf16.h>
#include <math.h>

typedef short s16x8 __attribute__((ext_vector_type(8)));
typedef float f32x4 __attribute__((ext_vector_type(4)));
typedef __hip_bfloat16 bf16;

#define NTOK 4096
#define S_LEN 2048
#define HID_C 1024
#define E_C 8
#define INTER_C 2816
#define WIN_C 64
#define CAP 4096
#define NQKV 1536
#define K2C 2048
#define ATILE 16
#define KR 80
#define OUT0_N ((size_t)NTOK*HID_C)

#define AS1 __attribute__((address_space(1)))
#define AS3 __attribute__((address_space(3)))

static __device__ __forceinline__ void gload16(const void* g, void* l){
    __builtin_amdgcn_global_load_lds((AS1 void*)(g), (AS3 void*)(l), 16, 0, 0);
}

static __device__ __forceinline__ float b2f(bf16 v){ return __bfloat162float(v); }
static __device__ __forceinline__ bf16  f2b(float v){ return __float2bfloat16(v); }
static __device__ __forceinline__ short f2bs(float v){ bf16 h = __float2bfloat16(v); return *reinterpret_cast<short*>(&h); }
struct SplitBF { short hi; short lo; };
static __device__ __forceinline__ SplitBF splitf(float x){
    SplitBF r;
    bf16 bh = __float2bfloat16(x);
    r.hi = *reinterpret_cast<short*>(&bh);
    float rem = x - __bfloat162float(bh);
    bf16 bl = __float2bfloat16(rem);
    r.lo = *reinterpret_cast<short*>(&bl);
    return r;
}

// Swizzle convention: within each 64-short (128B) group of a row, logical
// 8-short chunk c is stored at physical chunk c ^ (row & 7).

// ---------------- device bodies ----------------

static __device__ __forceinline__ void tsplit_body(char* smem, const float* __restrict__ src,
                                                   short* __restrict__ dst, int N, int row_off,
                                                   int bx, int by){
    float (*tile)[33] = (float(*)[33])smem;
    const int n0 = bx*32, k0 = by*32;
    const int tx = threadIdx.x & 31, ty = threadIdx.x >> 5;
    #pragma unroll
    for (int i = 0; i < 4; ++i)
        tile[ty + i*8][tx] = src[(size_t)(k0 + ty + i*8)*N + n0 + tx];
    __syncthreads();
    const int g = k0 >> 5;
    const int chH = tx >> 3, chL = 4 | (tx >> 3), off = tx & 7;
    #pragma unroll
    for (int i = 0; i < 4; ++i){
        int nn = ty + i*8;
        SplitBF s = splitf(tile[tx][nn]);
        size_t rowb = (size_t)(row_off + n0 + nn)*K2C + g*64;
        dst[rowb + ((chH ^ ty)<<3) + off] = s.hi;
        dst[rowb + ((chL ^ ty)<<3) + off] = s.lo;
    }
}

static __device__ __forceinline__ void rmsn1_body(char* smem, const float* __restrict__ xin,
                                                  const float* __restrict__ w,
                                                  short* __restrict__ oc, int t){
    float* red = (float*)smem;
    const int tid = threadIdx.x;
    float4 v = *(const float4*)(xin + (size_t)t*HID_C + tid*4);
    float x[4] = {v.x, v.y, v.z, v.w};
    float s = x[0]*x[0]+x[1]*x[1]+x[2]*x[2]+x[3]*x[3];
    #pragma unroll
    for (int off=32; off; off>>=1) s += __shfl_xor(s, off);
    if ((tid&63)==0) red[tid>>6] = s;
    __syncthreads();
    float tot = red[0]+red[1]+red[2]+red[3];
    float sc = rsqrtf(tot*(1.0f/HID_C) + 1e-8f);
    float4 wv = *(const float4*)(w + tid*4);
    float o[4] = { x[0]*sc*wv.x, x[1]*sc*wv.y, x[2]*sc*wv.z, x[3]*sc*wv.w };
    __align__(8) short th[4], tl[4];
    #pragma unroll
    for (int i=0;i<4;++i){ SplitBF sp = splitf(o[i]); th[i]=sp.hi; tl[i]=sp.lo; }
    const int g = tid>>3, q = tid&7;
    const int ch = q>>1, sub = (q&1)*4, key = t&7;
    short* rowp = oc + (size_t)t*K2C + g*64;
    *(uint2*)(rowp + ((ch ^ key)<<3) + sub)      = *(uint2*)th;
    *(uint2*)(rowp + (((4|ch) ^ key)<<3) + sub)  = *(uint2*)tl;
}

static __device__ __forceinline__ void tbf16_body(char* smem, const float* __restrict__ src0,
                                                  short* __restrict__ dst0, int K, int N,
                                                  int bx, int by, int e){
    const float* src = src0 + (size_t)e*K*N;
    short* dst = dst0 + (size_t)e*N*K;
    float (*tile)[65] = (float(*)[65])smem;
    const int n0 = bx*64, k0 = by*64;
    const int tid = threadIdx.x;
    #pragma unroll
    for (int i = 0; i < 16; ++i){
        int idx = tid + i*256;
        int k = idx >> 6, n = idx & 63;
        tile[k][n] = src[(size_t)(k0 + k)*N + n0 + n];
    }
    __syncthreads();
    const int grp = k0 >> 6;
    const int ch  = tid & 7;
    #pragma unroll
    for (int i = 0; i < 2; ++i){
        int nn = (tid >> 3) + i*32;
        int key = nn & 7;
        __align__(16) short vals[8];
        #pragma unroll
        for (int c = 0; c < 8; ++c) vals[c] = f2bs(tile[ch*8 + c][nn]);
        *(uint4*)(dst + (size_t)(n0 + nn)*K + grp*64 + ((ch ^ key)<<3)) = *(uint4*)vals;
    }
}

template<bool RESID>
static __device__ __forceinline__ void sgemm_body(char* smem, int bmi, int bni,
                                                  const short* __restrict__ A2,
                                                  const short* __restrict__ B2,
                                                  float* __restrict__ C,
                                                  const float* __restrict__ resid, int N){
    short* lA0 = (short*)smem;
    short* lB0 = (short*)(smem + 32768);
    const int tid = threadIdx.x;
    const int bm0 = bmi*128, bn0 = bni*128;
    const int l = tid & 63, w = tid >> 6, wr = w >> 1, wc = w & 1;
    const int lr = l >> 3, lc8 = (l & 7)*8;
    f32x4 acc[4][4] = {};
    auto STAGE = [&](int buf, int kt){
        #pragma unroll
        for (int j = 0; j < 4; ++j){
            int row = w*32 + j*8 + lr;
            gload16(A2 + (size_t)(bm0 + row)*K2C + kt*64 + lc8, lA0 + buf*8192 + (w*32 + j*8)*64);
            gload16(B2 + (size_t)(bn0 + row)*K2C + kt*64 + lc8, lB0 + buf*8192 + (w*32 + j*8)*64);
        }
    };
    STAGE(0, 0);
    for (int kt = 0; kt < 32; ++kt){
        const int cur = kt & 1;
        if (kt + 1 < 32){
            STAGE(cur ^ 1, kt + 1);
            asm volatile("s_waitcnt vmcnt(8)" ::: "memory");
        } else {
            asm volatile("s_waitcnt vmcnt(0)" ::: "memory");
        }
        __builtin_amdgcn_s_barrier();
        __builtin_amdgcn_sched_barrier(0);
        s16x8 ah[4], al[4], bh[4], bl[4];
        #pragma unroll
        for (int mi = 0; mi < 4; ++mi){
            int r = wr*64 + mi*16 + (l&15);
            int key = r & 7;
            ah[mi] = *(const s16x8*)(lA0 + cur*8192 + r*64 + (((l>>4) ^ key)<<3));
            al[mi] = *(const s16x8*)(lA0 + cur*8192 + r*64 + (((4|(l>>4)) ^ key)<<3));
        }
        #pragma unroll
        for (int ni = 0; ni < 4; ++ni){
            int n = wc*64 + ni*16 + (l&15);
            int key = n & 7;
            bh[ni] = *(const s16x8*)(lB0 + cur*8192 + n*64 + (((l>>4) ^ key)<<3));
            bl[ni] = *(const s16x8*)(lB0 + cur*8192 + n*64 + (((4|(l>>4)) ^ key)<<3));
        }
        #pragma unroll
        for (int mi = 0; mi < 4; ++mi)
            #pragma unroll
            for (int ni = 0; ni < 4; ++ni){
                acc[mi][ni] = __builtin_amdgcn_mfma_f32_16x16x32_bf16(ah[mi], bh[ni], acc[mi][ni], 0,0,0);
                acc[mi][ni] = __builtin_amdgcn_mfma_f32_16x16x32_bf16(ah[mi], bl[ni], acc[mi][ni], 0,0,0);
                acc[mi][ni] = __builtin_amdgcn_mfma_f32_16x16x32_bf16(al[mi], bh[ni], acc[mi][ni], 0,0,0);
            }
        __builtin_amdgcn_s_barrier();
    }
    #pragma unroll
    for (int mi = 0; mi < 4; ++mi)
        #pragma unroll
        for (int ni = 0; ni < 4; ++ni)
            #pragma unroll
            for (int rr = 0; rr < 4; ++rr){
                int row = bm0 + wr*64 + mi*16 + (l>>4)*4 + rr;
                int col = bn0 + wc*64 + ni*16 + (l&15);
                float vv = acc[mi][ni][rr];
                if (RESID) vv += resid[(size_t)row*N + col];
                C[(size_t)row*N + col] = vv;
            }
}

// ---------------- fused prepass 1 ----------------
__global__ __launch_bounds__(256) void prep1_k(const float* __restrict__ hidden,
                                               const float* __restrict__ n1w,
                                               short* __restrict__ h1c,
                                               const float* __restrict__ wq,
                                               const float* __restrict__ wk,
                                               const float* __restrict__ wv,
                                               const float* __restrict__ wo,
                                               short* __restrict__ wqkv2,
                                               short* __restrict__ wo2){
    __shared__ __align__(16) char smem[4352];
    const int b = blockIdx.x;
    if (b < 4096){
        rmsn1_body(smem, hidden, n1w, h1c, b);
    } else if (b < 5120){
        int r = b - 4096;
        tsplit_body(smem, wq, wqkv2, 1024, 0, r & 31, r >> 5);
    } else if (b < 5376){
        int r = b - 5120;
        tsplit_body(smem, wk, wqkv2, 256, 1024, r & 7, r >> 3);
    } else if (b < 5632){
        int r = b - 5376;
        tsplit_body(smem, wv, wqkv2, 256, 1280, r & 7, r >> 3);
    } else {
        int r = b - 5632;
        tsplit_body(smem, wo, wo2, 1024, 0, r & 31, r >> 5);
    }
}

// ---------------- fused prepass 2 ----------------
__global__ __launch_bounds__(256) void prep2_k(const short* __restrict__ h1c,
                                               const short* __restrict__ wqkv2,
                                               float* __restrict__ qkvf,
                                               const float* __restrict__ gatew,
                                               const float* __restrict__ upw,
                                               const float* __restrict__ downw,
                                               short* __restrict__ gate_t,
                                               short* __restrict__ up_t,
                                               short* __restrict__ down_t){
    __shared__ __align__(16) char smem[65536];
    const int b = blockIdx.x;
    if (b < 384){
        sgemm_body<false>(smem, b & 31, b >> 5, h1c, wqkv2, qkvf, nullptr, NQKV);
        return;
    }
    int r = b - 384;
    int wsel = r / 5632;
    int r2 = r % 5632;
    if (wsel == 0)      tbf16_body(smem, gatew, gate_t, 1024, 2816, r2 % 44, (r2/44) % 16, r2/704);
    else if (wsel == 1) tbf16_body(smem, upw,   up_t,   1024, 2816, r2 % 44, (r2/44) % 16, r2/704);
    else                tbf16_body(smem, downw, down_t, 2816, 1024, r2 % 16, (r2/16) % 44, r2/704);
}

template<bool RESID>
__global__ __launch_bounds__(256) void sgemm4_k(const short* __restrict__ A2,
                                                const short* __restrict__ B2,
                                                float* __restrict__ C, const float* __restrict__ resid,
                                                int N){
    __shared__ __align__(16) char smem[65536];
    sgemm_body<RESID>(smem, blockIdx.x, blockIdx.y, A2, B2, C, resid, N);
}

__global__ __launch_bounds__(256) void rmsn2_k(const float* __restrict__ xin,
                                               const float* __restrict__ w,
                                               float* __restrict__ outf, bf16* __restrict__ outb,
                                               float* __restrict__ outc){
    const int t = blockIdx.x, tid = threadIdx.x;
    float4 v = *(const float4*)(xin + (size_t)t*HID_C + tid*4);
    float x[4] = {v.x, v.y, v.z, v.w};
    float s = x[0]*x[0]+x[1]*x[1]+x[2]*x[2]+x[3]*x[3];
    #pragma unroll
    for (int off=32; off; off>>=1) s += __shfl_xor(s, off);
    __shared__ float red[4];
    if ((tid&63)==0) red[tid>>6] = s;
    __syncthreads();
    float tot = red[0]+red[1]+red[2]+red[3];
    float sc = rsqrtf(tot*(1.0f/HID_C) + 1e-8f);
    float4 wv = *(const float4*)(w + tid*4);
    float o[4] = { x[0]*sc*wv.x, x[1]*sc*wv.y, x[2]*sc*wv.z, x[3]*sc*wv.w };
    *(float4*)(outf + (size_t)t*HID_C + tid*4) = make_float4(o[0],o[1],o[2],o[3]);
    __align__(8) bf16 tmp[4] = { f2b(o[0]), f2b(o[1]), f2b(o[2]), f2b(o[3]) };
    *(uint2*)(outb + (size_t)t*HID_C + tid*4) = *(uint2*)tmp;
    *(float4*)(outc + (size_t)t*HID_C + tid*4) = v;
}

__global__ __launch_bounds__(256) void rope2_k(float* __restrict__ qkv,
                                               const float* __restrict__ cosb, const float* __restrict__ sinb){
    int idx = blockIdx.x*256 + threadIdx.x;
    int t = idx / 640;
    int r = idx - t*640;
    int hs = r >> 5, tp = r & 31;
    int s = t & (S_LEN-1);
    float c  = cosb[s*32+tp];
    float sn = sinb[s*32+tp];
    float* base;
    if (hs < 16) base = qkv + (size_t)t*NQKV + hs*64 + 2*tp;
    else         base = qkv + (size_t)t*NQKV + 1024 + (hs-16)*64 + 2*tp;
    float2 v = *(float2*)base;
    *(float2*)base = make_float2(v.x*c - v.y*sn, v.x*sn + v.y*c);
}

__global__ __launch_bounds__(256) void attn3_k(const float* __restrict__ qkv,
                                               short* __restrict__ oc){
    const int t0 = blockIdx.x * ATILE;
    const int hk = blockIdx.y;
    const int sq0 = t0 & (S_LEN-1);
    const int tokbase = t0 - sq0;
    const int tid = threadIdx.x, l = tid & 63, w = tid >> 6;
    __shared__ float Kl[KR*65];
    __shared__ float Vl[KR*65];
    __shared__ float qsh[4][64];
    __shared__ float ps[4][64];
    for (int rr = tid >> 4; rr < KR; rr += 16){
        int c4 = (tid & 15)*4;
        int kp = sq0 - 64 + rr;
        float4 kv = make_float4(0,0,0,0), vv = kv;
        if (kp >= 0){
            const float* base = qkv + (size_t)(tokbase + kp)*NQKV + 1024 + hk*64 + c4;
            kv = *(const float4*)base;
            vv = *(const float4*)(base + 256);
        }
        Kl[rr*65 + c4+0]=kv.x; Kl[rr*65 + c4+1]=kv.y; Kl[rr*65 + c4+2]=kv.z; Kl[rr*65 + c4+3]=kv.w;
        Vl[rr*65 + c4+0]=vv.x; Vl[rr*65 + c4+1]=vv.y; Vl[rr*65 + c4+2]=vv.z; Vl[rr*65 + c4+3]=vv.w;
    }
    __syncthreads();
    const int h = hk*4 + w;
    for (int i = 0; i < ATILE; ++i){
        const int t = t0 + i, sq = sq0 + i;
        qsh[w][l] = qkv[(size_t)t*NQKV + h*64 + l];
        float d = 0.f;
        const float* krow = &Kl[(i + l)*65];
        #pragma unroll
        for (int c = 0; c < 64; ++c) d += qsh[w][c] * krow[c];
        const bool valid = (sq - 64 + l) >= 0;
        float sc = valid ? d*0.125f : -1e30f;
        float part = qsh[w][l] * Kl[(i + 64)*65 + l];
        #pragma unroll
        for (int off = 32; off; off >>= 1) part += __shfl_xor(part, off);
        float dg = part*0.125f;
        float m = sc;
        #pragma unroll
        for (int off = 32; off; off >>= 1) m = fmaxf(m, __shfl_xor(m, off));
        m = fmaxf(m, dg);
        float e = __expf(sc - m);
        float ssum = e;
        #pragma unroll
        for (int off = 32; off; off >>= 1) ssum += __shfl_xor(ssum, off);
        float edg = __expf(dg - m);
        ssum += edg;
        float inv = 1.f / ssum;
        ps[w][l] = e * inv;
        float pdg = edg * inv;
        float acc = 0.f;
        #pragma unroll 8
        for (int jj = 0; jj < 64; ++jj) acc += ps[w][jj] * Vl[(i + jj)*65 + l];
        acc += pdg * Vl[(i + 64)*65 + l];
        SplitBF sp = splitf(acc);
        const int k = h*64 + l;
        const int g = k>>5, ch = (k&31)>>3, off2 = k&7, key = t&7;
        short* rowp = oc + (size_t)t*K2C + g*64;
        rowp[((ch ^ key)<<3) + off2]     = sp.hi;
        rowp[(((4|ch) ^ key)<<3) + off2] = sp.lo;
    }
}

__global__ __launch_bounds__(256) void router2_k(const float* __restrict__ h2f, const float* __restrict__ rw,
                                                 int* __restrict__ lists, float* __restrict__ wl,
                                                 int* __restrict__ cnt, float* __restrict__ psum){
    const int tid = threadIdx.x, l = tid & 63, w = tid >> 6;
    __shared__ int   sE0[16], sE1[16], sSlot0[16], sSlot1[16];
    __shared__ float sW0[16], sW1[16];
    __shared__ float sPsum[8];
    __shared__ int   sCnt[8], sBase[8];
    if (tid < 8){ sPsum[tid] = 0.f; sCnt[tid] = 0; }
    __syncthreads();
    #pragma unroll
    for (int i = 0; i < 4; ++i){
        const int li = w*4 + i;
        const int t = blockIdx.x*16 + li;
        float lg[8] = {0,0,0,0,0,0,0,0};
        for (int c = 0; c < 16; ++c){
            int kidx = l + c*64;
            float x = h2f[(size_t)t*HID_C + kidx];
            float4 w0 = *(const float4*)(rw + (size_t)kidx*8);
            float4 w1 = *(const float4*)(rw + (size_t)kidx*8 + 4);
            lg[0] += x*w0.x; lg[1] += x*w0.y; lg[2] += x*w0.z; lg[3] += x*w0.w;
            lg[4] += x*w1.x; lg[5] += x*w1.y; lg[6] += x*w1.z; lg[7] += x*w1.w;
        }
        #pragma unroll
        for (int e = 0; e < 8; ++e)
            #pragma unroll
            for (int off=32; off; off>>=1) lg[e] += __shfl_xor(lg[e], off);
        if (l == 0){
            float m = lg[0];
            #pragma unroll
            for (int e = 1; e < 8; ++e) m = fmaxf(m, lg[e]);
            float p[8]; float s = 0.f;
            #pragma unroll
            for (int e = 0; e < 8; ++e){ p[e] = __expf(lg[e]-m); s += p[e]; }
            float invs = 1.f/s;
            #pragma unroll
            for (int e = 0; e < 8; ++e){ p[e] *= invs; atomicAdd(&sPsum[e], p[e]); }
            float best = -1e30f, sec = -1e30f; int bi = 0, si = 0;
            #pragma unroll
            for (int e = 0; e < 8; ++e){
                float pv = p[e];
                if (pv > best){ sec = best; si = bi; best = pv; bi = e; }
                else if (pv > sec){ sec = pv; si = e; }
            }
            float wsum = best + sec + 1e-9f;
            sE0[li] = bi; sE1[li] = si;
            sW0[li] = best/wsum; sW1[li] = sec/wsum;
            sSlot0[li] = atomicAdd(&sCnt[bi], 1);
            sSlot1[li] = atomicAdd(&sCnt[si], 1);
        }
    }
    __syncthreads();
    if (tid < 8){
        sBase[tid] = atomicAdd(&cnt[tid], sCnt[tid]);
        atomicAdd(&psum[tid], sPsum[tid]);
    }
    __syncthreads();
    if (tid < 16){
        int t = blockIdx.x*16 + tid;
        int e0 = sE0[tid], e1 = sE1[tid];
        int s0 = sBase[e0] + sSlot0[tid];
        int s1 = sBase[e1] + sSlot1[tid];
        lists[e0*CAP + s0] = t; wl[e0*CAP + s0] = sW0[tid];
        lists[e1*CAP + s1] = t; wl[e1*CAP + s1] = sW1[tid];
    }
}

__global__ void finalize_k(const int* __restrict__ cnt, const float* __restrict__ psum,
                           int* __restrict__ offs, float* __restrict__ out){
    if (threadIdx.x == 0 && blockIdx.x == 0){
        int o = 0; float loss = 0.f;
        for (int e = 0; e < 8; ++e){
            offs[e] = o; o += cnt[e];
            loss += (psum[e]*(1.0f/NTOK)) * ((float)cnt[e]*(1.0f/NTOK));
        }
        offs[8] = o;
        out[OUT0_N] = loss * (float)E_C * 0.01f;
    }
}

// ============ MoE gate/up: XCD panel-grouped, dbuf gload16, A-source swizzle, setprio ============
__global__ __launch_bounds__(256) void moe1g3_k(const short* __restrict__ h2b,
                                                const short* __restrict__ gate_t,
                                                const short* __restrict__ up_t,
                                                bf16* __restrict__ inter,
                                                const int* __restrict__ lists,
                                                const int* __restrict__ cnt,
                                                const int* __restrict__ offs){
    const int b = blockIdx.x;
    const int r = b & 7, j = b >> 3;
    const int G = r + ((j >> 5) << 3);
    const int e = G / 44, bnG = G % 44;
    const int bm0 = (j & 31) * 128;
    const int ne = cnt[e];
    if (bm0 >= ne) return;
    const int bn0 = bnG * 64;
    __shared__ __align__(16) short lA[2][128*64];
    __shared__ __align__(16) short lG[2][64*64];
    __shared__ __align__(16) short lU[2][64*64];
    const int tid = threadIdx.x;
    const int l = tid & 63, w = tid >> 6, wr = w >> 1, wc = w & 1;
    const int lr = l >> 3, lc8 = (l & 7)*8;
    const int lcs = (((l & 7) ^ lr) << 3);
    const short* Gb = gate_t + (size_t)e*INTER_C*HID_C;
    const short* Ub = up_t   + (size_t)e*INTER_C*HID_C;
    int tokA[4];
    #pragma unroll
    for (int jj = 0; jj < 4; ++jj){
        int slot = bm0 + w*32 + jj*8 + lr;
        if (slot >= ne) slot = ne - 1;
        tokA[jj] = lists[e*CAP + slot];
    }
    auto STAGE = [&](int buf, int kt){
        #pragma unroll
        for (int jj = 0; jj < 4; ++jj)
            gload16(h2b + (size_t)tokA[jj]*HID_C + kt*64 + lcs, &lA[buf][(w*32 + jj*8)*64]);
        #pragma unroll
        for (int jj = 0; jj < 2; ++jj){
            int n = w*16 + jj*8 + lr;
            gload16(Gb + (size_t)(bn0 + n)*HID_C + kt*64 + lc8, &lG[buf][(w*16 + jj*8)*64]);
            gload16(Ub + (size_t)(bn0 + n)*HID_C + kt*64 + lc8, &lU[buf][(w*16 + jj*8)*64]);
        }
    };
    f32x4 ag[4][2] = {}; f32x4 au[4][2] = {};
    STAGE(0, 0);
    for (int kt = 0; kt < 16; ++kt){
        const int cur = kt & 1;
        if (kt + 1 < 16){
            STAGE(cur ^ 1, kt + 1);
            asm volatile("s_waitcnt vmcnt(8)" ::: "memory");
        } else {
            asm volatile("s_waitcnt vmcnt(0)" ::: "memory");
        }
        __builtin_amdgcn_s_barrier();
        __builtin_amdgcn_sched_barrier(0);
        __builtin_amdgcn_s_setprio(1);
        #pragma unroll
        for (int kk = 0; kk < 64; kk += 32){
            s16x8 af[4], bg[2], bu[2];
            #pragma unroll
            for (int mi = 0; mi < 4; ++mi){
                int ra = wr*64 + mi*16 + (l&15);
                int keyA = ra & 7;
                int chA = (kk>>3) + (l>>4);
                af[mi] = *(const s16x8*)(&lA[cur][ra*64 + ((chA ^ keyA)<<3)]);
            }
            #pragma unroll
            for (int ni = 0; ni < 2; ++ni){
                int n = wc*32 + ni*16 + (l&15);
                int key = n & 7;
                int ch = (kk>>3) + (l>>4);
                bg[ni] = *(const s16x8*)(&lG[cur][n*64 + ((ch ^ key)<<3)]);
                bu[ni] = *(const s16x8*)(&lU[cur][n*64 + ((ch ^ key)<<3)]);
            }
            #pragma unroll
            for (int mi = 0; mi < 4; ++mi)
                #pragma unroll
                for (int ni = 0; ni < 2; ++ni){
                    ag[mi][ni] = __builtin_amdgcn_mfma_f32_16x16x32_bf16(af[mi], bg[ni], ag[mi][ni], 0,0,0);
                    au[mi][ni] = __builtin_amdgcn_mfma_f32_16x16x32_bf16(af[mi], bu[ni], au[mi][ni], 0,0,0);
                }
        }
        __builtin_amdgcn_s_setprio(0);
        __builtin_amdgcn_s_barrier();
    }
    const int obase = offs[e];
    #pragma unroll
    for (int mi = 0; mi < 4; ++mi)
        #pragma unroll
        for (int ni = 0; ni < 2; ++ni)
            #pragma unroll
            for (int rr = 0; rr < 4; ++rr){
                int slot = bm0 + wr*64 + mi*16 + (l>>4)*4 + rr;
                if (slot < ne){
                    int col = bn0 + wc*32 + ni*16 + (l&15);
                    float g = ag[mi][ni][rr], uu = au[mi][ni][rr];
                    float val = (g/(1.f+__expf(-g)))*uu;
                    inter[(size_t)(obase+slot)*INTER_C + col] = f2b(val);
                }
            }
}

// ============ MoE down: XCD panel-grouped, dbuf gload16, A-source swizzle, setprio; atomics into out ============
__global__ __launch_bounds__(256) void moe2g3_k(const bf16* __restrict__ inter,
                                                const short* __restrict__ down_t,
                                                float* __restrict__ outp,
                                                const float* __restrict__ wl,
                                                const int* __restrict__ lists,
                                                const int* __restrict__ cnt,
                                                const int* __restrict__ offs){
    const int b = blockIdx.x;
    const int r = b & 7, j = b >> 3;
    const int G = r + ((j >> 5) << 3);
    const int e = G >> 3, bnG = G & 7;
    const int bm0 = (j & 31) * 128;
    const int ne = cnt[e];
    if (bm0 >= ne) return;
    const int bn0 = bnG * 128;
    __shared__ __align__(16) short lA[2][128*64];
    __shared__ __align__(16) short lB[2][128*64];
    const int tid = threadIdx.x;
    const int l = tid & 63, w = tid >> 6, wr = w >> 1, wc = w & 1;
    const int lr = l >> 3, lc8 = (l & 7)*8;
    const int lcs = (((l & 7) ^ lr) << 3);
    const int obase = offs[e];
    const short* Db = down_t + (size_t)e*HID_C*INTER_C;
    const short* As = (const short*)inter;
    int rowA[4];
    #pragma unroll
    for (int jj = 0; jj < 4; ++jj){
        int slot = bm0 + w*32 + jj*8 + lr;
        if (slot >= ne) slot = ne - 1;
        rowA[jj] = obase + slot;
    }
    auto STAGE = [&](int buf, int kt){
        #pragma unroll
        for (int jj = 0; jj < 4; ++jj){
            gload16(As + (size_t)rowA[jj]*INTER_C + kt*64 + lcs, &lA[buf][(w*32 + jj*8)*64]);
            int n = w*32 + jj*8 + lr;
            gload16(Db + (size_t)(bn0 + n)*INTER_C + kt*64 + lc8, &lB[buf][(w*32 + jj*8)*64]);
        }
    };
    f32x4 acc[4][4] = {};
    STAGE(0, 0);
    for (int kt = 0; kt < 44; ++kt){
        const int cur = kt & 1;
        if (kt + 1 < 44){
            STAGE(cur ^ 1, kt + 1);
            asm volatile("s_waitcnt vmcnt(8)" ::: "memory");
        } else {
            asm volatile("s_waitcnt vmcnt(0)" ::: "memory");
        }
        __builtin_amdgcn_s_barrier();
        __builtin_amdgcn_sched_barrier(0);
        __builtin_amdgcn_s_setprio(1);
        #pragma unroll
        for (int kk = 0; kk < 64; kk += 32){
            s16x8 af[4], bfr[4];
            #pragma unroll
            for (int mi = 0; mi < 4; ++mi){
                int ra = wr*64 + mi*16 + (l&15);
                int keyA = ra & 7;
                int chA = (kk>>3) + (l>>4);
                af[mi] = *(const s16x8*)(&lA[cur][ra*64 + ((chA ^ keyA)<<3)]);
            }
            #pragma unroll
            for (int ni = 0; ni < 4; ++ni){
                int n = wc*64 + ni*16 + (l&15);
                int key = n & 7;
                int ch = (kk>>3) + (l>>4);
                bfr[ni] = *(const s16x8*)(&lB[cur][n*64 + ((ch ^ key)<<3)]);
            }
            #pragma unroll
            for (int mi = 0; mi < 4; ++mi)
                #pragma unroll
                for (int ni = 0; ni < 4; ++ni)
                    acc[mi][ni] = __builtin_amdgcn_mfma_f32_16x16x32_bf16(af[mi], bfr[ni], acc[mi][ni], 0,0,0);
        }
        __builtin_amdgcn_s_setprio(0);
        __builtin_amdgcn_s_barrier();
    }
    #pragma unroll
    for (int mi = 0; mi < 4; ++mi)
        #pragma unroll
        for (int ni = 0; ni < 4; ++ni)
            #pragma unroll
            for (int rr = 0; rr < 4; ++rr){
                int slot = bm0 + wr*64 + mi*16 + (l>>4)*4 + rr;
                if (slot < ne){
                    int col = bn0 + wc*64 + ni*16 + (l&15);
                    int tok = lists[e*CAP + slot];
                    float wgt = wl[e*CAP + slot];
                    atomicAdd(&outp[(size_t)tok*HID_C + col], acc[mi][ni][rr]*wgt);
                }
            }
}

// ======================= HOST =======================
extern "C" void kernel_launch(void* const* d_in, const int* in_sizes, int n_in,
                              void* d_out, int out_size, void* d_ws, size_t ws_size,
                              hipStream_t stream){
    const float* hidden  = (const float*)d_in[0];
    const float* fcos    = (const float*)d_in[1];
    const float* fsin    = (const float*)d_in[2];
    const float* wq      = (const float*)d_in[3];
    const float* wk      = (const float*)d_in[4];
    const float* wv      = (const float*)d_in[5];
    const float* wo      = (const float*)d_in[6];
    const float* routerw = (const float*)d_in[7];
    const float* gatew   = (const float*)d_in[8];
    const float* upw     = (const float*)d_in[9];
    const float* downw   = (const float*)d_in[10];
    const float* n1w     = (const float*)d_in[11];
    const float* n2w     = (const float*)d_in[12];

    char* p = (char*)d_ws;
    size_t off = 0;
    auto alloc = [&](size_t b)->void*{ void* r = p + off; off = (off + b + 255) & ~(size_t)255; return r; };

    int*   cnt    = (int*)alloc(64);
    float* psum   = (float*)alloc(64);
    int*   offs   = (int*)alloc(64);
    int*   lists  = (int*)alloc((size_t)E_C*CAP*4);
    float* wl     = (float*)alloc((size_t)E_C*CAP*4);
    short* wqkv2  = (short*)alloc((size_t)NQKV*K2C*2);
    short* wo2    = (short*)alloc((size_t)HID_C*K2C*2);
    short* gate_t = (short*)alloc((size_t)E_C*INTER_C*HID_C*2);
    short* up_t   = (short*)alloc((size_t)E_C*INTER_C*HID_C*2);
    short* down_t = (short*)alloc((size_t)E_C*HID_C*INTER_C*2);
    short* h1c    = (short*)alloc((size_t)NTOK*K2C*2);
    float* qkvf   = (float*)alloc((size_t)NTOK*NQKV*4);
    float* hres   = (float*)alloc((size_t)NTOK*HID_C*4);
    bf16*  inter  = (bf16*)alloc((size_t)2*NTOK*INTER_C*2);

    short* oc  = h1c;
    float* h2f = qkvf;
    bf16*  h2b = (bf16*)(qkvf + (size_t)NTOK*HID_C);
    float* outp = (float*)d_out;

    (void)hipMemsetAsync(cnt, 0, 64, stream);
    (void)hipMemsetAsync(psum, 0, 64, stream);

    prep1_k<<<6656, 256, 0, stream>>>(hidden, n1w, h1c, wq, wk, wv, wo, wqkv2, wo2);
    prep2_k<<<384 + 16896, 256, 0, stream>>>(h1c, wqkv2, qkvf, gatew, upw, downw, gate_t, up_t, down_t);
    rope2_k<<<10240, 256, 0, stream>>>(qkvf, fcos, fsin);
    attn3_k<<<dim3(NTOK/ATILE, 4), 256, 0, stream>>>(qkvf, oc);
    sgemm4_k<true><<<dim3(32,8), 256, 0, stream>>>(oc, wo2, hres, hidden, 1024);
    rmsn2_k<<<NTOK, 256, 0, stream>>>(hres, n2w, h2f, h2b, outp);
    router2_k<<<256, 256, 0, stream>>>(h2f, routerw, lists, wl, cnt, psum);
    finalize_k<<<1, 64, 0, stream>>>(cnt, psum, offs, outp);
    moe1g3_k<<<11264, 256, 0, stream>>>((const short*)h2b, gate_t, up_t, inter, lists, cnt, offs);
    moe2g3_k<<<2048, 256, 0, stream>>>(inter, down_t, outp, wl, lists, cnt, offs);
}